// Round 3
// baseline (675.031 us; speedup 1.0000x reference)
//
#include <hip/hip_runtime.h>
#include <cfloat>

// VQ forward, MI355X. z[16,256,32,32] f32, emb[8192,256] f32, proj[256,256] f32.
// N = 16384 rows, K = 8192 codes, D = 256.
// d_out (floats): out[4194304] | loss | commitment | codebook_loss | idx_as_float[16384]
//
// R8 three-phase argmin:
//  scanA (bf16 MFMA): per-row global approx-min (atomicMin u32 monof).
//  k_thresh: thr[n] = min + DLT, DLT=1e-3 >> worst-case score error 3.2e-4.
//  scanC (bit-identical computation): emit k with sc <= thr[n] into per-row slots.
//  k_rescore: exact fp32 rescore of slots; packed (monof<<32|k) min -> first-index ties.
//
// R11: k_scan de-LDS'd on the B path. R9's per-phase double-buffer FAILED (162 vs
//  150 us) because __syncthreads always emits s_waitcnt vmcnt(0) -> every phase
//  drained the prefetch anyway. Resource audit: ds_read_b128 traffic (10/phase)
//  was 63% of cycle budget; MFMA only 10%. New structure:
//   - B fragments: global->VGPR short8 gathers (16 cols x 64 B segments, L2-hot,
//     XCD-local via kb swizzle), register double-buffer, 1-phase prefetch,
//     NO barriers in the main loop (compiler emits counted vmcnt only).
//   - A: zs LDS tile staged once (global_load_lds, swizzled), ONE barrier total,
//     2 ds_read_b128/phase.
//   - norms preloaded per-kt before the B prefetch chain (older loads -> their
//     wait doesn't drain newer B prefetches).
//  Same fragments, same MFMA order -> scores bit-identical to R9/R8 chain.

constexpr int Dd = 256;
constexpr float INV_M = 1.0f / 4194304.0f;
constexpr float DLT = 1e-3f;

typedef unsigned short u16;
typedef unsigned int u32;
typedef __attribute__((ext_vector_type(8))) short short8;   // 8 bf16
typedef __attribute__((ext_vector_type(4))) float f32x4;

#define GLOBAL_AS __attribute__((address_space(1)))
#define LDS_AS    __attribute__((address_space(3)))

__device__ __forceinline__ unsigned monof(float f) {
  unsigned u = __float_as_uint(f);
  return (u & 0x80000000u) ? ~u : (u | 0x80000000u);
}
__device__ __forceinline__ float unmonof(unsigned p) {
  unsigned u = (p & 0x80000000u) ? (p & 0x7FFFFFFFu) : ~p;
  return __uint_as_float(u);
}
__device__ __forceinline__ u16 f2bf(float x) {   // RNE float->bf16 bits
  unsigned u = __float_as_uint(x);
  u += 0x7FFFu + ((u >> 16) & 1u);
  return (u16)(u >> 16);
}

// ---- K1: codebook = emb @ proj^T -> cb[k][d] fp32 + eh bf16[k][d] ----
__global__ __launch_bounds__(256)
void k_codebook(const float* __restrict__ emb, const float* __restrict__ proj,
                float* __restrict__ cb, u16* __restrict__ eh) {
  __shared__ float et[64 * 65];
  __shared__ float pt[64 * 65];
  const int t = threadIdx.x;
  const int tx = t & 15, ty = t >> 4;
  const int kb = blockIdx.x * 64;
  const int db = blockIdx.y * 64;
  float acc[4][4];
#pragma unroll
  for (int u = 0; u < 4; ++u)
#pragma unroll
    for (int v = 0; v < 4; ++v) acc[u][v] = 0.f;

  const int jm = t & 15;
  const int q  = t >> 4;

  for (int jc = 0; jc < Dd; jc += 64) {
    __syncthreads();
#pragma unroll
    for (int i = 0; i < 4; ++i) {
      const int row = q + i * 16;
      const float4 e4 = *(const float4*)(emb  + (size_t)(kb + row) * Dd + jc + jm * 4);
      const float4 p4 = *(const float4*)(proj + (size_t)(db + row) * Dd + jc + jm * 4);
      et[(jm*4 + 0) * 65 + row] = e4.x;
      et[(jm*4 + 1) * 65 + row] = e4.y;
      et[(jm*4 + 2) * 65 + row] = e4.z;
      et[(jm*4 + 3) * 65 + row] = e4.w;
      pt[(jm*4 + 0) * 65 + row] = p4.x;
      pt[(jm*4 + 1) * 65 + row] = p4.y;
      pt[(jm*4 + 2) * 65 + row] = p4.z;
      pt[(jm*4 + 3) * 65 + row] = p4.w;
    }
    __syncthreads();
#pragma unroll 16
    for (int j = 0; j < 64; ++j) {
      float a[4], b[4];
#pragma unroll
      for (int u = 0; u < 4; ++u) a[u] = et[j*65 + ty*4 + u];
#pragma unroll
      for (int v = 0; v < 4; ++v) b[v] = pt[j*65 + tx*4 + v];
#pragma unroll
      for (int u = 0; u < 4; ++u)
#pragma unroll
        for (int v = 0; v < 4; ++v) acc[u][v] = fmaf(a[u], b[v], acc[u][v]);
    }
  }
#pragma unroll
  for (int u = 0; u < 4; ++u) {
    const int k = kb + ty*4 + u;
#pragma unroll
    for (int v = 0; v < 4; ++v) {
      const int d = db + tx*4 + v;
      const float val = acc[u][v];
      cb[(size_t)k * Dd + d] = val;
      eh[(size_t)k * Dd + d] = f2bf(val);
    }
  }
}

// ---- K1b: per-code norms (ascending-d fmaf chain) ----
__global__ __launch_bounds__(256)
void k_norms(const float* __restrict__ cb, float* __restrict__ norms) {
  const int k = blockIdx.x * 256 + threadIdx.x;
  const float* row = cb + (size_t)k * Dd;
  float s = 0.f;
  for (int d = 0; d < Dd; d += 4) {
    const float4 v = *(const float4*)(row + d);
    s = fmaf(v.x, v.x, s);
    s = fmaf(v.y, v.y, s);
    s = fmaf(v.z, v.z, s);
    s = fmaf(v.w, v.w, s);
  }
  norms[k] = s;
}

// ---- K1c: transpose z -> zh bf16 [n][d] + znorm ----
__global__ __launch_bounds__(256)
void k_prep_z(const float* __restrict__ z, u16* __restrict__ zh,
              float* __restrict__ znorm) {
  __shared__ float tile[256 * 33];
  const int t = threadIdx.x;
  const int blk = blockIdx.x;            // b*32 + h
  const int w = t & 31, rg = t >> 5;
  const size_t zbase = (size_t)(blk >> 5) * 262144 + (size_t)(blk & 31) * 32 + w;
#pragma unroll 8
  for (int i = 0; i < 32; ++i) {
    const int d = rg * 32 + i;
    tile[d * 33 + w] = z[zbase + (size_t)d * 1024];
  }
  __syncthreads();
  if (t < 32) {
    float s = 0.f;
    for (int d = 0; d < Dd; ++d) {
      const float v = tile[d * 33 + t];
      s = fmaf(v, v, s);
    }
    znorm[blk * 32 + t] = s;
  }
  const int nl = t >> 3, seg = t & 7;
  const size_t obase = (size_t)(blk * 32 + nl) * Dd + seg * 32;
#pragma unroll
  for (int j = 0; j < 4; ++j) {
    u16 hb[8];
#pragma unroll
    for (int e = 0; e < 8; ++e)
      hb[e] = f2bf(tile[(seg * 32 + j * 8 + e) * 33 + nl]);
    *(uint4*)(zh + obase + j * 8) = *(const uint4*)hb;
  }
}

// ---- K2: MFMA scan, B-streaming. Block 64 rows x 1024 cols; 4 waves 2x2. ----
// zs (A): 64 rows x 32 chunks (16B), slot = c ^ ((row&7)<<2) -> 32 KB, staged once,
//   ONE barrier, then 2 ds_read_b128/phase.
// B: per-phase 8 x short8 global gathers per wave, register double-buffer (static
//   parity), prefetch distance 1 phase, no barriers -> loads stay in flight.
template <bool EMIT>
__global__ __launch_bounds__(256, 2)
void k_scan(const u16* __restrict__ zh, const u16* __restrict__ eh,
            const float* __restrict__ norms, const float* __restrict__ znorm,
            u32* __restrict__ rowminG, const float* __restrict__ rowThr,
            u32* __restrict__ rowcnt, u16* __restrict__ slots) {
  __shared__ __align__(16) u16 zs[64 * 256];      // 32 KB
  const int t    = threadIdx.x;
  const int lane = t & 63;
  const int ml   = lane & 15;
  const int qd   = lane >> 4;
  const int wvu  = __builtin_amdgcn_readfirstlane(t >> 6);
  const int rowhalf = wvu & 1;           // 0/1 -> 32 rows
  const int colhalf = wvu >> 1;          // 0/1 -> 128 cols (of kt's 256)
  const int bid  = blockIdx.x;
  const int kb   = (bid & 7) * 1024;     // colgroup -> XCD-local eh reuse
  const int nb   = (bid >> 3) * 64;

  // ---- stage zs once: wave wvu covers rows [wvu*16, +16) ----
#pragma unroll
  for (int i = 0; i < 8; ++i) {
    const int r0 = wvu * 16 + i * 2;
    const int row_l = r0 + (lane >> 5);
    const int c = (lane & 31) ^ ((row_l & 7) << 2);
    const u16* gp = zh + (size_t)(nb + row_l) * 256 + c * 8;
    __builtin_amdgcn_global_load_lds((const GLOBAL_AS void*)gp,
                                     (LDS_AS void*)(zs + r0 * 256), 16, 0, 0);
  }
  __syncthreads();   // the ONLY barrier: zs ready (drains only the 8 zs loads)

  // ---- per-lane B base: col = kb + kt*256 + colhalf*128 + ct*16 + ml ----
  // eb covers ct=0,kt=0; per-ct add ct*4096 (compile-time), per-phase uniform off.
  const u16* eb = eh + (size_t)(kb + colhalf * 128 + ml) * 256 + qd * 8;

  // per-thread rows: n = nb + rowhalf*32 + rt*16 + qd*4 + r
  float zn[2][4], thr[2][4];
#pragma unroll
  for (int rt = 0; rt < 2; ++rt) {
    const int nr = nb + rowhalf * 32 + rt * 16 + qd * 4;
    const f32x4 z4 = *(const f32x4*)(znorm + nr);
#pragma unroll
    for (int r = 0; r < 4; ++r) zn[rt][r] = z4[r];
    if (EMIT) {
      const f32x4 t4 = *(const f32x4*)(rowThr + nr);
#pragma unroll
      for (int r = 0; r < 4; ++r) thr[rt][r] = t4[r];
    }
  }

  float mv[2][4];
#pragma unroll
  for (int rt = 0; rt < 2; ++rt)
#pragma unroll
    for (int r = 0; r < 4; ++r) mv[rt][r] = FLT_MAX;

  short8 B0[8], B1[8];
  // prologue: phase 0 (kt=0, dhp=0) into B0
#pragma unroll
  for (int ct = 0; ct < 8; ++ct)
    B0[ct] = *(const short8*)(eb + ct * 4096);

#pragma unroll 1
  for (int kt = 0; kt < 4; ++kt) {
    // norms for this kt's 128 cols — issued BEFORE this kt's B prefetches so
    // their wait never drains newer loads.
    float nk[8];
#pragma unroll
    for (int ct = 0; ct < 8; ++ct)
      nk[ct] = norms[kb + kt * 256 + colhalf * 128 + ct * 16 + ml];

    f32x4 acc[2][8];
#pragma unroll
    for (int rt = 0; rt < 2; ++rt)
#pragma unroll
      for (int ct = 0; ct < 8; ++ct) acc[rt][ct] = (f32x4)0.f;

#pragma unroll
    for (int dhp = 0; dhp < 8; ++dhp) {
      // prefetch next phase's B into the other buffer (uniform offset; no guard
      // needed except the very last phase)
      if (kt * 8 + dhp + 1 < 32) {
        const int pn = kt * 8 + dhp + 1;
        const int offn = (pn >> 3) * 65536 + (pn & 7) * 32;
        if (dhp & 1) {
#pragma unroll
          for (int ct = 0; ct < 8; ++ct)
            B0[ct] = *(const short8*)(eb + ct * 4096 + offn);
        } else {
#pragma unroll
          for (int ct = 0; ct < 8; ++ct)
            B1[ct] = *(const short8*)(eb + ct * 4096 + offn);
        }
      }

      // A fragments from LDS (2 reads)
      short8 Af[2];
#pragma unroll
      for (int rt = 0; rt < 2; ++rt) {
        const int row_l = rowhalf * 32 + rt * 16 + ml;
        const int cg = dhp * 4 + qd;
        const int slot = cg ^ ((row_l & 7) << 2);
        Af[rt] = *(const short8*)(zs + row_l * 256 + slot * 8);
      }

      if (dhp & 1) {
#pragma unroll
        for (int rt = 0; rt < 2; ++rt)
#pragma unroll
          for (int ct = 0; ct < 8; ++ct)
            acc[rt][ct] = __builtin_amdgcn_mfma_f32_16x16x32_bf16(
                Af[rt], B1[ct], acc[rt][ct], 0, 0, 0);
      } else {
#pragma unroll
        for (int rt = 0; rt < 2; ++rt)
#pragma unroll
          for (int ct = 0; ct < 8; ++ct)
            acc[rt][ct] = __builtin_amdgcn_mfma_f32_16x16x32_bf16(
                Af[rt], B0[ct], acc[rt][ct], 0, 0, 0);
      }
    }

    // fold this kt's 128 cols (per thread: 8 cols via ct, rows via rt,r)
#pragma unroll
    for (int ct = 0; ct < 8; ++ct) {
      const int k = kb + kt * 256 + colhalf * 128 + ct * 16 + ml;
      const float nkv = nk[ct];
#pragma unroll
      for (int rt = 0; rt < 2; ++rt)
#pragma unroll
        for (int r = 0; r < 4; ++r) {
          const float sc = (zn[rt][r] + nkv) - 2.0f * acc[rt][ct][r];
          if (!EMIT) {
            mv[rt][r] = fminf(mv[rt][r], sc);
          } else if (sc <= thr[rt][r]) {
            const int n = nb + rowhalf * 32 + rt * 16 + qd * 4 + r;
            const u32 pos = atomicAdd(&rowcnt[n], 1u);
            if (pos < 32u) slots[n * 32 + pos] = (u16)k;
          }
        }
    }
  }

  if (!EMIT) {
#pragma unroll
    for (int rt = 0; rt < 2; ++rt)
#pragma unroll
      for (int r = 0; r < 4; ++r) {
        float m = mv[rt][r];
#pragma unroll
        for (int s = 1; s < 16; s <<= 1) m = fminf(m, __shfl_xor(m, s, 64));
        if (ml == 0)
          atomicMin(&rowminG[nb + rowhalf * 32 + rt * 16 + qd * 4 + r], monof(m));
      }
  }
}

// ---- K2b: threshold ----
__global__ __launch_bounds__(256)
void k_thresh(const u32* __restrict__ rowminG, float* __restrict__ rowThr) {
  const int n = blockIdx.x * 256 + threadIdx.x;
  rowThr[n] = unmonof(rowminG[n]) + DLT;
}

// ---- K2c: exact rescore of slot candidates ----
// Block per (b,h): 32 rows; LDS z-tile [32][261] fp32; wave per 8 rows.
__global__ __launch_bounds__(256)
void k_rescore(const float* __restrict__ z, const float* __restrict__ cb,
               const float* __restrict__ norms, const float* __restrict__ znorm,
               const u32* __restrict__ rowcnt, const u16* __restrict__ slots,
               unsigned long long* __restrict__ packed) {
  __shared__ float ztl[32 * 261];
  const int t = threadIdx.x;
  const int blk = blockIdx.x;          // b*32 + h
  const int w = t & 31, dg = t >> 5;
  const size_t zbase = (size_t)(blk >> 5) * 262144 + (size_t)(blk & 31) * 32;
#pragma unroll 8
  for (int i = 0; i < 32; ++i) {
    const int d = dg * 32 + i;
    ztl[w * 261 + d] = z[zbase + (size_t)d * 1024 + w];
  }
  __syncthreads();

  const int lane = t & 63;
  const int wv = t >> 6;               // 4 waves
  // 4 waves x 8 rows each
#pragma unroll 1
  for (int i = 0; i < 8; ++i) {
    const int rl = wv * 8 + i;
    const int n = blk * 32 + rl;
    const u32 cnt = min(rowcnt[n], 32u);
    const float znr = znorm[n];
    unsigned long long best = 0xFFFFFFFFFFFFFFFFull;
    for (u32 c = 0; c < cnt; ++c) {
      const int k = (int)slots[n * 32 + c];
      const float4 c4 = *(const float4*)(cb + (size_t)k * Dd + lane * 4);
      const float* zp = ztl + rl * 261 + lane * 4;
      float p = 0.f;
      p = fmaf(zp[0], c4.x, p);
      p = fmaf(zp[1], c4.y, p);
      p = fmaf(zp[2], c4.z, p);
      p = fmaf(zp[3], c4.w, p);
#pragma unroll
      for (int s = 1; s < 64; s <<= 1) p += __shfl_xor(p, s, 64);
      const float sc = (znr + norms[k]) - 2.0f * p;   // quantized fold
      const unsigned long long pk =
          ((unsigned long long)monof(sc) << 32) | (unsigned)k;
      if (pk < best) best = pk;                        // lexicographic: ties -> min k
    }
    if (lane == 0 && cnt > 0) packed[n] = best;
  }
}

// ---- K3: gather codes, write out (NCHW), idx floats, reduce SSE ----
__global__ __launch_bounds__(256)
void k_output(const float* __restrict__ z, const float* __restrict__ cb,
              const unsigned long long* __restrict__ packed,
              float* __restrict__ out, float* __restrict__ idxf,
              float* __restrict__ ssum) {
  __shared__ float zqT[256 * 33];
  __shared__ float part[4];
  const int t = threadIdx.x;
  const int blk = blockIdx.x;       // = b*32 + h
  const int nbase = blk * 32;

  {
    const int nl = t >> 3, m = t & 7;
    const int idx = (int)(packed[nbase + nl] & 0xFFFFFFFFull);
    const float* row = cb + (size_t)idx * Dd;
#pragma unroll
    for (int i = 0; i < 8; ++i) {
      const int d0 = m * 4 + i * 32;
      const float4 v = *(const float4*)(row + d0);
      zqT[(d0 + 0) * 33 + nl] = v.x;
      zqT[(d0 + 1) * 33 + nl] = v.y;
      zqT[(d0 + 2) * 33 + nl] = v.z;
      zqT[(d0 + 3) * 33 + nl] = v.w;
    }
    if (t < 32)
      idxf[nbase + t] = (float)(unsigned)(packed[nbase + t] & 0xFFFFFFFFull);
  }
  __syncthreads();

  const int w = t & 31, cg = t >> 5;
  const size_t base = (size_t)(blk >> 5) * 262144 + (size_t)(blk & 31) * 32 + w;
  float local = 0.f;
#pragma unroll
  for (int cc = 0; cc < 32; ++cc) {
    const int c = cg * 32 + cc;
    const float q  = zqT[c * 33 + w];
    const float zv = z[base + (size_t)c * 1024];
    out[base + (size_t)c * 1024] = q;
    const float dd = q - zv;
    local = fmaf(dd, dd, local);
  }
  float v = local;
#pragma unroll
  for (int m = 1; m < 64; m <<= 1) v += __shfl_xor(v, m, 64);
  if ((t & 63) == 0) part[t >> 6] = v;
  __syncthreads();
  if (t == 0) atomicAdd(ssum, part[0] + part[1] + part[2] + part[3]);
}

// ---- K4: finalize scalars ----
__global__ void k_final(const float* __restrict__ ssum, float* __restrict__ scal) {
  const float m = *ssum * INV_M;
  scal[0] = 1.25f * m;   // loss
  scal[1] = 0.25f * m;   // commitment_loss
  scal[2] = m;           // codebook_loss
}

extern "C" void kernel_launch(void* const* d_in, const int* in_sizes, int n_in,
                              void* d_out, int out_size, void* d_ws, size_t ws_size,
                              hipStream_t stream) {
  const float* z    = (const float*)d_in[0];
  const float* emb  = (const float*)d_in[1];
  const float* proj = (const float*)d_in[2];

  float* out  = (float*)d_out;
  float* scal = out + 4194304;
  float* idxf = out + 4194307;

  // ws (~22 MB): cb | norms | packed | znorm | zh | eh | rowminG | rowThr | rowcnt | slots | ssum
  float* cb    = (float*)d_ws;                          // 8 MB
  float* norms = cb + 2097152;                          // 32 KB
  unsigned long long* packed =
      (unsigned long long*)(norms + 8192);              // 128 KB
  float* znorm = (float*)(packed + 16384);              // 64 KB
  u16* zh = (u16*)(znorm + 16384);                      // 8.4 MB
  u16* eh = zh + 4194304;                               // 4.2 MB
  u32* rowminG = (u32*)(eh + 2097152);                  // 64 KB
  float* rowThr = (float*)(rowminG + 16384);            // 64 KB
  u32* rowcnt = (u32*)(rowThr + 16384);                 // 64 KB
  u16* slots = (u16*)(rowcnt + 16384);                  // 1 MB
  float* ssum = (float*)(slots + 16384 * 32);           // 4 B

  hipMemsetAsync(rowminG, 0xFF, 16384 * sizeof(u32), stream);
  hipMemsetAsync(rowcnt, 0, 16384 * sizeof(u32), stream);
  hipMemsetAsync(packed, 0xFF, 16384 * sizeof(unsigned long long), stream);
  hipMemsetAsync(ssum, 0, sizeof(float), stream);

  k_codebook<<<dim3(128, 4), 256, 0, stream>>>(emb, proj, cb, eh);
  k_norms   <<<32, 256, 0, stream>>>(cb, norms);
  k_prep_z  <<<512, 256, 0, stream>>>(z, zh, znorm);
  k_scan<false><<<2048, 256, 0, stream>>>(zh, eh, norms, znorm,
                                          rowminG, rowThr, rowcnt, slots);
  k_thresh  <<<64, 256, 0, stream>>>(rowminG, rowThr);
  k_scan<true> <<<2048, 256, 0, stream>>>(zh, eh, norms, znorm,
                                          rowminG, rowThr, rowcnt, slots);
  k_rescore <<<512, 256, 0, stream>>>(z, cb, norms, znorm, rowcnt, slots, packed);
  k_output  <<<512, 256, 0, stream>>>(z, cb, packed, out, idxf, ssum);
  k_final   <<<1, 1, 0, stream>>>(ssum, scal);

  (void)in_sizes; (void)n_in; (void)out_size; (void)ws_size;
}

// Round 4
// 416.363 us; speedup vs baseline: 1.6213x; 1.6213x over previous
//
#include <hip/hip_runtime.h>
#include <cfloat>

// VQ forward, MI355X. z[16,256,32,32] f32, emb[8192,256] f32, proj[256,256] f32.
// N = 16384 rows, K = 8192 codes, D = 256.
// d_out (floats): out[4194304] | loss | commitment | codebook_loss | idx_as_float[16384]
//
// R8 three-phase argmin:
//  scanA (bf16 MFMA): per-row global approx-min (atomicMin u32 monof).
//  k_thresh: thr[n] = min + DLT, DLT=1e-3 >> worst-case score error 3.2e-4.
//  scanC (bit-identical computation): emit k with sc <= thr[n] into per-row slots.
//  k_rescore: exact fp32 rescore of slots; packed (monof<<32|k) min -> first-index ties.
//
// R12: fragment-ordered operands. R11's global-B gathers were 16-line scatters
//  (+ probable spills) -> 268 us, MfmaUtil 10%. Root cause of the whole k_scan
//  plateau: LDS round-trips (R0/R9) or scattered gathers (R11) to feed fragments.
//  Fix: store BOTH operands in MFMA-fragment order, produced by our own prep
//  kernels:  granule(16B) index U = (row16 * 8 + d32)*64 + qd*16 + (row&15),
//  content = bf16[row][d32*32 + qd*8 .. +8].  One wave fragment = 64 lanes x 16B
//  CONTIGUOUS = one coalesced global_load_dwordx4 (1 KB).  k_scan then has NO
//  LDS and NO barriers: A,B stream global->VGPR (L1/L2-hot, XCD-local kb),
//  register double-buffer, distance-1 prefetch, compiler counted-vmcnt.
//  Same wave mapping / MFMA order as R0 chain -> scores bit-identical.

constexpr int Dd = 256;
constexpr float INV_M = 1.0f / 4194304.0f;
constexpr float DLT = 1e-3f;

typedef unsigned short u16;
typedef unsigned int u32;
typedef __attribute__((ext_vector_type(8))) short short8;   // 8 bf16
typedef __attribute__((ext_vector_type(4))) float f32x4;

__device__ __forceinline__ unsigned monof(float f) {
  unsigned u = __float_as_uint(f);
  return (u & 0x80000000u) ? ~u : (u | 0x80000000u);
}
__device__ __forceinline__ float unmonof(unsigned p) {
  unsigned u = (p & 0x80000000u) ? (p & 0x7FFFFFFFu) : ~p;
  return __uint_as_float(u);
}
__device__ __forceinline__ u16 f2bf(float x) {   // RNE float->bf16 bits
  unsigned u = __float_as_uint(x);
  u += 0x7FFFu + ((u >> 16) & 1u);
  return (u16)(u >> 16);
}

// ---- K1: codebook = emb @ proj^T -> cb[k][d] fp32 + ef bf16 fragment-order ----
__global__ __launch_bounds__(256)
void k_codebook(const float* __restrict__ emb, const float* __restrict__ proj,
                float* __restrict__ cb, u16* __restrict__ ef) {
  __shared__ float et[64 * 65];
  __shared__ float pt[64 * 65];
  __shared__ __align__(16) u16 tileT[64 * 72];
  const int t = threadIdx.x;
  const int tx = t & 15, ty = t >> 4;
  const int kb = blockIdx.x * 64;
  const int db = blockIdx.y * 64;
  float acc[4][4];
#pragma unroll
  for (int u = 0; u < 4; ++u)
#pragma unroll
    for (int v = 0; v < 4; ++v) acc[u][v] = 0.f;

  const int jm = t & 15;
  const int q  = t >> 4;

  for (int jc = 0; jc < Dd; jc += 64) {
    __syncthreads();
#pragma unroll
    for (int i = 0; i < 4; ++i) {
      const int row = q + i * 16;
      const float4 e4 = *(const float4*)(emb  + (size_t)(kb + row) * Dd + jc + jm * 4);
      const float4 p4 = *(const float4*)(proj + (size_t)(db + row) * Dd + jc + jm * 4);
      et[(jm*4 + 0) * 65 + row] = e4.x;
      et[(jm*4 + 1) * 65 + row] = e4.y;
      et[(jm*4 + 2) * 65 + row] = e4.z;
      et[(jm*4 + 3) * 65 + row] = e4.w;
      pt[(jm*4 + 0) * 65 + row] = p4.x;
      pt[(jm*4 + 1) * 65 + row] = p4.y;
      pt[(jm*4 + 2) * 65 + row] = p4.z;
      pt[(jm*4 + 3) * 65 + row] = p4.w;
    }
    __syncthreads();
#pragma unroll 16
    for (int j = 0; j < 64; ++j) {
      float a[4], b[4];
#pragma unroll
      for (int u = 0; u < 4; ++u) a[u] = et[j*65 + ty*4 + u];
#pragma unroll
      for (int v = 0; v < 4; ++v) b[v] = pt[j*65 + tx*4 + v];
#pragma unroll
      for (int u = 0; u < 4; ++u)
#pragma unroll
        for (int v = 0; v < 4; ++v) acc[u][v] = fmaf(a[u], b[v], acc[u][v]);
    }
  }
  // fp32 cb (linear) + bf16 tile to LDS for fragment-order shuffle
#pragma unroll
  for (int u = 0; u < 4; ++u) {
    const int k = kb + ty*4 + u;
#pragma unroll
    for (int v = 0; v < 4; ++v) {
      const int d = db + tx*4 + v;
      const float val = acc[u][v];
      cb[(size_t)k * Dd + d] = val;
      tileT[(ty*4 + u) * 72 + tx*4 + v] = f2bf(val);
    }
  }
  __syncthreads();
  // emit 512 fragment granules (16 B each), coalesced
  uint4* ef16 = (uint4*)ef;
#pragma unroll
  for (int w2 = 0; w2 < 2; ++w2) {
    const int uu = w2 * 256 + t;
    const int k16g = uu >> 7;            // 0..3 (16-k group within tile)
    const int d32g = (uu >> 6) & 1;      // 0..1 (32-d group within tile)
    const int ln   = uu & 63;            // fragment lane
    const int klo  = k16g * 16 + (ln & 15);
    const int dlo  = d32g * 32 + (ln >> 4) * 8;
    ef16[((kb >> 4) + k16g) * 512 + ((db >> 5) + d32g) * 64 + ln] =
        *(const uint4*)&tileT[klo * 72 + dlo];
  }
}

// ---- K1b: per-code norms (ascending-d fmaf chain) ----
__global__ __launch_bounds__(256)
void k_norms(const float* __restrict__ cb, float* __restrict__ norms) {
  const int k = blockIdx.x * 256 + threadIdx.x;
  const float* row = cb + (size_t)k * Dd;
  float s = 0.f;
  for (int d = 0; d < Dd; d += 4) {
    const float4 v = *(const float4*)(row + d);
    s = fmaf(v.x, v.x, s);
    s = fmaf(v.y, v.y, s);
    s = fmaf(v.z, v.z, s);
    s = fmaf(v.w, v.w, s);
  }
  norms[k] = s;
}

// ---- K1c: transpose z -> zf bf16 fragment-order + znorm ----
__global__ __launch_bounds__(256)
void k_prep_z(const float* __restrict__ z, u16* __restrict__ zf,
              float* __restrict__ znorm) {
  __shared__ float tile[256 * 33];
  const int t = threadIdx.x;
  const int blk = blockIdx.x;            // b*32 + h
  const int w = t & 31, rg = t >> 5;
  const size_t zbase = (size_t)(blk >> 5) * 262144 + (size_t)(blk & 31) * 32 + w;
#pragma unroll 8
  for (int i = 0; i < 32; ++i) {
    const int d = rg * 32 + i;
    tile[d * 33 + w] = z[zbase + (size_t)d * 1024];
  }
  __syncthreads();
  if (t < 32) {
    float s = 0.f;
    for (int d = 0; d < Dd; ++d) {
      const float v = tile[d * 33 + t];
      s = fmaf(v, v, s);
    }
    znorm[blk * 32 + t] = s;
  }
  // fragment-order write: granule U = ((n>>4)*8 + d32)*64 + qd*16 + (n&15)
  // thread remap keeps consecutive lanes -> consecutive granules (coalesced)
  const int ml16 = t & 15;
  const int seg  = (t >> 4) & 7;         // d32 group
  const int hi   = t >> 7;               // n16 group within block (0/1)
  const int nl   = hi * 16 + ml16;       // row 0..31 within block
  uint4* zf16 = (uint4*)zf;
  const int ubase = ((blk * 2 + hi) * 8 + seg) * 64 + ml16;
#pragma unroll
  for (int j = 0; j < 4; ++j) {          // qd octet
    u16 hb[8];
#pragma unroll
    for (int e = 0; e < 8; ++e)
      hb[e] = f2bf(tile[(seg * 32 + j * 8 + e) * 33 + nl]);
    zf16[ubase + j * 16] = *(const uint4*)hb;
  }
}

// ---- K2: MFMA scan, all-register streaming. Block 64 rows x 1024 cols. ----
// No LDS, no barriers. A,B fragments = coalesced 1KB loads from fragment-ordered
// zf/ef; register double-buffer, distance-1 prefetch; compiler counted vmcnt.
template <bool EMIT>
__global__ __launch_bounds__(256, 2)
void k_scan(const u16* __restrict__ zf, const u16* __restrict__ ef,
            const float* __restrict__ norms, const float* __restrict__ znorm,
            u32* __restrict__ rowminG, const float* __restrict__ rowThr,
            u32* __restrict__ rowcnt, u16* __restrict__ slots) {
  const int t    = threadIdx.x;
  const int lane = t & 63;
  const int ml   = lane & 15;
  const int qd   = lane >> 4;
  const int wvu  = __builtin_amdgcn_readfirstlane(t >> 6);
  const int rowhalf = wvu & 1;           // 0/1 -> 32 rows
  const int colhalf = wvu >> 1;          // 0/1 -> 128 cols (of kt's 256)
  const int bid  = blockIdx.x;
  const int kb   = (bid & 7) * 1024;     // colgroup -> XCD-local ef reuse
  const int nb   = (bid >> 3) * 64;

  // per-lane fragment base pointers (16-B granule units)
  const uint4* za = (const uint4*)zf + (size_t)((nb >> 4) + rowhalf * 2) * 512 + lane;
  // A granule for (rt, d32): za + rt*512 + d32*64
  const uint4* eb = (const uint4*)ef + (size_t)((kb >> 4) + colhalf * 8) * 512 + lane;
  // B granule for (kt, ct, d32): eb + kt*8192 + ct*512 + d32*64

  // per-thread rows: n = nb + rowhalf*32 + rt*16 + qd*4 + r
  float zn[2][4], thr[2][4];
#pragma unroll
  for (int rt = 0; rt < 2; ++rt) {
    const int nr = nb + rowhalf * 32 + rt * 16 + qd * 4;
    const f32x4 z4 = *(const f32x4*)(znorm + nr);
#pragma unroll
    for (int r = 0; r < 4; ++r) zn[rt][r] = z4[r];
    if (EMIT) {
      const f32x4 t4 = *(const f32x4*)(rowThr + nr);
#pragma unroll
      for (int r = 0; r < 4; ++r) thr[rt][r] = t4[r];
    }
  }

  float mv[2][4];
#pragma unroll
  for (int rt = 0; rt < 2; ++rt)
#pragma unroll
    for (int r = 0; r < 4; ++r) mv[rt][r] = FLT_MAX;

  short8 A0[2], A1[2], B0[8], B1[8];
  // prologue: phase 0 (kt=0, d32=0) into buf0
#pragma unroll
  for (int rt = 0; rt < 2; ++rt) A0[rt] = *(const short8*)(za + rt * 512);
#pragma unroll
  for (int ct = 0; ct < 8; ++ct) B0[ct] = *(const short8*)(eb + ct * 512);

#pragma unroll 1
  for (int kt = 0; kt < 4; ++kt) {
    float nk[8];
#pragma unroll
    for (int ct = 0; ct < 8; ++ct)
      nk[ct] = norms[kb + kt * 256 + colhalf * 128 + ct * 16 + ml];

    f32x4 acc[2][8];
#pragma unroll
    for (int rt = 0; rt < 2; ++rt)
#pragma unroll
      for (int ct = 0; ct < 8; ++ct) acc[rt][ct] = (f32x4)0.f;

#pragma unroll
    for (int dhp = 0; dhp < 8; ++dhp) {
      const int pn = kt * 8 + dhp + 1;
      if (pn < 32) {                       // prefetch next phase
        const int offa = (pn & 7) * 64;
        const int offb = (pn >> 3) * 8192 + (pn & 7) * 64;
        if (dhp & 1) {
#pragma unroll
          for (int rt = 0; rt < 2; ++rt)
            A0[rt] = *(const short8*)(za + rt * 512 + offa);
#pragma unroll
          for (int ct = 0; ct < 8; ++ct)
            B0[ct] = *(const short8*)(eb + ct * 512 + offb);
        } else {
#pragma unroll
          for (int rt = 0; rt < 2; ++rt)
            A1[rt] = *(const short8*)(za + rt * 512 + offa);
#pragma unroll
          for (int ct = 0; ct < 8; ++ct)
            B1[ct] = *(const short8*)(eb + ct * 512 + offb);
        }
      }
      if (dhp & 1) {
#pragma unroll
        for (int rt = 0; rt < 2; ++rt)
#pragma unroll
          for (int ct = 0; ct < 8; ++ct)
            acc[rt][ct] = __builtin_amdgcn_mfma_f32_16x16x32_bf16(
                A1[rt], B1[ct], acc[rt][ct], 0, 0, 0);
      } else {
#pragma unroll
        for (int rt = 0; rt < 2; ++rt)
#pragma unroll
          for (int ct = 0; ct < 8; ++ct)
            acc[rt][ct] = __builtin_amdgcn_mfma_f32_16x16x32_bf16(
                A0[rt], B0[ct], acc[rt][ct], 0, 0, 0);
      }
    }

    // fold this kt's 128 cols (per thread: 8 cols via ct, rows via rt,r)
#pragma unroll
    for (int ct = 0; ct < 8; ++ct) {
      const int k = kb + kt * 256 + colhalf * 128 + ct * 16 + ml;
      const float nkv = nk[ct];
#pragma unroll
      for (int rt = 0; rt < 2; ++rt)
#pragma unroll
        for (int r = 0; r < 4; ++r) {
          const float sc = (zn[rt][r] + nkv) - 2.0f * acc[rt][ct][r];
          if (!EMIT) {
            mv[rt][r] = fminf(mv[rt][r], sc);
          } else if (sc <= thr[rt][r]) {
            const int n = nb + rowhalf * 32 + rt * 16 + qd * 4 + r;
            const u32 pos = atomicAdd(&rowcnt[n], 1u);
            if (pos < 32u) slots[n * 32 + pos] = (u16)k;
          }
        }
    }
  }

  if (!EMIT) {
#pragma unroll
    for (int rt = 0; rt < 2; ++rt)
#pragma unroll
      for (int r = 0; r < 4; ++r) {
        float m = mv[rt][r];
#pragma unroll
        for (int s = 1; s < 16; s <<= 1) m = fminf(m, __shfl_xor(m, s, 64));
        if (ml == 0)
          atomicMin(&rowminG[nb + rowhalf * 32 + rt * 16 + qd * 4 + r], monof(m));
      }
  }
}

// ---- K2b: threshold ----
__global__ __launch_bounds__(256)
void k_thresh(const u32* __restrict__ rowminG, float* __restrict__ rowThr) {
  const int n = blockIdx.x * 256 + threadIdx.x;
  rowThr[n] = unmonof(rowminG[n]) + DLT;
}

// ---- K2c: exact rescore of slot candidates ----
// Block per (b,h): 32 rows; LDS z-tile [32][261] fp32; wave per 8 rows.
__global__ __launch_bounds__(256)
void k_rescore(const float* __restrict__ z, const float* __restrict__ cb,
               const float* __restrict__ norms, const float* __restrict__ znorm,
               const u32* __restrict__ rowcnt, const u16* __restrict__ slots,
               unsigned long long* __restrict__ packed) {
  __shared__ float ztl[32 * 261];
  const int t = threadIdx.x;
  const int blk = blockIdx.x;          // b*32 + h
  const int w = t & 31, dg = t >> 5;
  const size_t zbase = (size_t)(blk >> 5) * 262144 + (size_t)(blk & 31) * 32;
#pragma unroll 8
  for (int i = 0; i < 32; ++i) {
    const int d = dg * 32 + i;
    ztl[w * 261 + d] = z[zbase + (size_t)d * 1024 + w];
  }
  __syncthreads();

  const int lane = t & 63;
  const int wv = t >> 6;               // 4 waves
  // 4 waves x 8 rows each
#pragma unroll 1
  for (int i = 0; i < 8; ++i) {
    const int rl = wv * 8 + i;
    const int n = blk * 32 + rl;
    const u32 cnt = min(rowcnt[n], 32u);
    const float znr = znorm[n];
    unsigned long long best = 0xFFFFFFFFFFFFFFFFull;
    for (u32 c = 0; c < cnt; ++c) {
      const int k = (int)slots[n * 32 + c];
      const float4 c4 = *(const float4*)(cb + (size_t)k * Dd + lane * 4);
      const float* zp = ztl + rl * 261 + lane * 4;
      float p = 0.f;
      p = fmaf(zp[0], c4.x, p);
      p = fmaf(zp[1], c4.y, p);
      p = fmaf(zp[2], c4.z, p);
      p = fmaf(zp[3], c4.w, p);
#pragma unroll
      for (int s = 1; s < 64; s <<= 1) p += __shfl_xor(p, s, 64);
      const float sc = (znr + norms[k]) - 2.0f * p;   // quantized fold
      const unsigned long long pk =
          ((unsigned long long)monof(sc) << 32) | (unsigned)k;
      if (pk < best) best = pk;                        // lexicographic: ties -> min k
    }
    if (lane == 0 && cnt > 0) packed[n] = best;
  }
}

// ---- K3: gather codes, write out (NCHW), idx floats, reduce SSE ----
__global__ __launch_bounds__(256)
void k_output(const float* __restrict__ z, const float* __restrict__ cb,
              const unsigned long long* __restrict__ packed,
              float* __restrict__ out, float* __restrict__ idxf,
              float* __restrict__ ssum) {
  __shared__ float zqT[256 * 33];
  __shared__ float part[4];
  const int t = threadIdx.x;
  const int blk = blockIdx.x;       // = b*32 + h
  const int nbase = blk * 32;

  {
    const int nl = t >> 3, m = t & 7;
    const int idx = (int)(packed[nbase + nl] & 0xFFFFFFFFull);
    const float* row = cb + (size_t)idx * Dd;
#pragma unroll
    for (int i = 0; i < 8; ++i) {
      const int d0 = m * 4 + i * 32;
      const float4 v = *(const float4*)(row + d0);
      zqT[(d0 + 0) * 33 + nl] = v.x;
      zqT[(d0 + 1) * 33 + nl] = v.y;
      zqT[(d0 + 2) * 33 + nl] = v.z;
      zqT[(d0 + 3) * 33 + nl] = v.w;
    }
    if (t < 32)
      idxf[nbase + t] = (float)(unsigned)(packed[nbase + t] & 0xFFFFFFFFull);
  }
  __syncthreads();

  const int w = t & 31, cg = t >> 5;
  const size_t base = (size_t)(blk >> 5) * 262144 + (size_t)(blk & 31) * 32 + w;
  float local = 0.f;
#pragma unroll
  for (int cc = 0; cc < 32; ++cc) {
    const int c = cg * 32 + cc;
    const float q  = zqT[c * 33 + w];
    const float zv = z[base + (size_t)c * 1024];
    out[base + (size_t)c * 1024] = q;
    const float dd = q - zv;
    local = fmaf(dd, dd, local);
  }
  float v = local;
#pragma unroll
  for (int m = 1; m < 64; m <<= 1) v += __shfl_xor(v, m, 64);
  if ((t & 63) == 0) part[t >> 6] = v;
  __syncthreads();
  if (t == 0) atomicAdd(ssum, part[0] + part[1] + part[2] + part[3]);
}

// ---- K4: finalize scalars ----
__global__ void k_final(const float* __restrict__ ssum, float* __restrict__ scal) {
  const float m = *ssum * INV_M;
  scal[0] = 1.25f * m;   // loss
  scal[1] = 0.25f * m;   // commitment_loss
  scal[2] = m;           // codebook_loss
}

extern "C" void kernel_launch(void* const* d_in, const int* in_sizes, int n_in,
                              void* d_out, int out_size, void* d_ws, size_t ws_size,
                              hipStream_t stream) {
  const float* z    = (const float*)d_in[0];
  const float* emb  = (const float*)d_in[1];
  const float* proj = (const float*)d_in[2];

  float* out  = (float*)d_out;
  float* scal = out + 4194304;
  float* idxf = out + 4194307;

  // ws (~22 MB): cb | norms | packed | znorm | zf | ef | rowminG | rowThr | rowcnt | slots | ssum
  float* cb    = (float*)d_ws;                          // 8 MB
  float* norms = cb + 2097152;                          // 32 KB
  unsigned long long* packed =
      (unsigned long long*)(norms + 8192);              // 128 KB
  float* znorm = (float*)(packed + 16384);              // 64 KB
  u16* zf = (u16*)(znorm + 16384);                      // 8.4 MB (fragment-order)
  u16* ef = zf + 4194304;                               // 4.2 MB (fragment-order)
  u32* rowminG = (u32*)(ef + 2097152);                  // 64 KB
  float* rowThr = (float*)(rowminG + 16384);            // 64 KB
  u32* rowcnt = (u32*)(rowThr + 16384);                 // 64 KB
  u16* slots = (u16*)(rowcnt + 16384);                  // 1 MB
  float* ssum = (float*)(slots + 16384 * 32);           // 4 B

  hipMemsetAsync(rowminG, 0xFF, 16384 * sizeof(u32), stream);
  hipMemsetAsync(rowcnt, 0, 16384 * sizeof(u32), stream);
  hipMemsetAsync(packed, 0xFF, 16384 * sizeof(unsigned long long), stream);
  hipMemsetAsync(ssum, 0, sizeof(float), stream);

  k_codebook<<<dim3(128, 4), 256, 0, stream>>>(emb, proj, cb, ef);
  k_norms   <<<32, 256, 0, stream>>>(cb, norms);
  k_prep_z  <<<512, 256, 0, stream>>>(z, zf, znorm);
  k_scan<false><<<2048, 256, 0, stream>>>(zf, ef, norms, znorm,
                                          rowminG, rowThr, rowcnt, slots);
  k_thresh  <<<64, 256, 0, stream>>>(rowminG, rowThr);
  k_scan<true> <<<2048, 256, 0, stream>>>(zf, ef, norms, znorm,
                                          rowminG, rowThr, rowcnt, slots);
  k_rescore <<<512, 256, 0, stream>>>(z, cb, norms, znorm, rowcnt, slots, packed);
  k_output  <<<512, 256, 0, stream>>>(z, cb, packed, out, idxf, ssum);
  k_final   <<<1, 1, 0, stream>>>(ssum, scal);

  (void)in_sizes; (void)n_in; (void)out_size; (void)ws_size;
}